// Round 1
// baseline (2630.119 us; speedup 1.0000x reference)
//
#include <hip/hip_runtime.h>
#include <hip/hip_bf16.h>

#define B_   32
#define S_   200
#define H_   512
#define ED_  256
#define NF_  19
#define NROW (B_*S_)      // 6400
#define G4H  (4*H_)       // 2048
#define KIN  (ED_+NF_)    // 275
#define KP_  288          // padded K for input GEMM
#define ALD  296          // A-tile LDS row stride (bf16): 592 B = 37 superbanks (odd)
#define HP   520          // h-stage LDS row stride (bf16): 1040 B = 65 superbanks (odd)

typedef __attribute__((ext_vector_type(8))) short short8;
typedef __attribute__((ext_vector_type(4))) float f32x4;

// ---------------- workspace layout (bytes) ----------------
#define OFF_G0   0ull
#define SZ_G0    ((size_t)NROW*G4H*4)            // 52428800
#define OFF_LSTM (OFF_G0 + SZ_G0)
#define SZ_LSTM  ((size_t)NROW*H_*4)             // 13107200
#define OFF_CT   (OFF_LSTM + SZ_LSTM)
#define SZ_CT    ((size_t)NROW*NF_*4)            // 486400
#define OFF_CN   (OFF_CT + SZ_CT)
#define OFF_H0   (OFF_CN + SZ_CT)
#define SZ_HB    ((size_t)2*B_*H_*2)             // 65536 (bf16 double buffer)
#define OFF_H1   (OFF_H0 + SZ_HB)
#define OFF_SYNC (OFF_H1 + SZ_HB)                // [0]=barrier counter u32, [1]=num f32, [2]=den f32
#define OFF_WB   (OFF_SYNC + 256)                // Wih0 pre-converted bf16 [2048][288]
#define SZ_WB    ((size_t)G4H*KP_*2)             // 1179648

__device__ __forceinline__ unsigned short f2bf(float f) {
    unsigned u = __float_as_uint(f);
    unsigned r = u + 0x7fffu + ((u >> 16) & 1u);
    return (unsigned short)(r >> 16);
}
__device__ __forceinline__ float sigf(float x) { return 1.0f / (1.0f + __expf(-x)); }

// ---------------- prep: c_t/c_next, h-buffer init, sync zero ----------------
__global__ __launch_bounds__(256) void prep_kernel(
    const float* __restrict__ C, const float* __restrict__ rep,
    const float* __restrict__ past, const float* __restrict__ seq,
    const float* __restrict__ init_h,
    float* __restrict__ ct, float* __restrict__ cn,
    unsigned short* __restrict__ h0buf, unsigned short* __restrict__ h1buf,
    unsigned* __restrict__ syncbuf)
{
    int idx = blockIdx.x * 256 + threadIdx.x;
    if (idx < NROW * NF_) {
        int m = idx % NF_; int row = idx / NF_;
        int b = row / S_, s = row % S_;
        float cc = C[idx];
        float v0, v1;
        if (m < 7)       { v0 = rep [(b*(S_+1)+s)*7 + m];      v1 = rep [(b*(S_+1)+s+1)*7 + m]; }
        else if (m < 13) { v0 = seq [(b*(S_+1)+s)*6 + (m-7)];  v1 = seq [(b*(S_+1)+s+1)*6 + (m-7)]; }
        else             { v0 = past[(b*(S_+1)+s)*6 + (m-13)]; v1 = past[(b*(S_+1)+s+1)*6 + (m-13)]; }
        ct[idx] = cc * v0;
        cn[idx] = cc * v1;
    }
    int j = idx - NROW * NF_;
    if (j >= 0 && j < B_ * H_) {
        h0buf[j] = f2bf(init_h[j]);
        h1buf[j] = f2bf(init_h[B_ * H_ + j]);
    }
    if (j >= B_ * H_ && j < B_ * H_ + 4) syncbuf[j - B_ * H_] = 0u;
}

// ---------------- prep_w: Wih0 f32[2048][275] -> bf16[2048][288] (zero-pad) ----------------
__global__ __launch_bounds__(256) void prepw_kernel(
    const float* __restrict__ Wih0, unsigned short* __restrict__ wb)
{
    int idx = blockIdx.x * 256 + threadIdx.x;
    if (idx >= G4H * KP_) return;
    int k = idx % KP_; int r = idx / KP_;
    wb[idx] = (k < KIN) ? f2bf(Wih0[(size_t)r * KIN + k]) : (unsigned short)0;
}

// ---------------- G0 = [emb|c_t] @ Wih0^T + bih0 + bhh0  (bf16 MFMA) ----------------
__global__ __launch_bounds__(256) void g0_kernel(
    const int* __restrict__ x_data, const float* __restrict__ embed,
    const unsigned short* __restrict__ wb,
    const float* __restrict__ bih0, const float* __restrict__ bhh0,
    const float* __restrict__ ct, float* __restrict__ G0)
{
    __shared__ unsigned short A[32 * ALD];
    int tid = threadIdx.x;
    int bx = blockIdx.x;
    int mb = bx >> 5;          // 0..199  (row tile of 32)
    int nb = bx & 31;          // 0..31   (col tile of 64)
    int rbase = mb * 32;
    {   // stage A: 32 gathered rows of [emb(256)|c_t(19)|pad]
        int r = tid >> 3, c8 = tid & 7;
        int grow = rbase + r;
        const float* erow = embed + (size_t)x_data[grow] * ED_;
        #pragma unroll
        for (int jj = 0; jj < 8; jj++) {
            float4 v = *(const float4*)(erow + c8 * 32 + jj * 4);
            unsigned short* d = &A[r * ALD + c8 * 32 + jj * 4];
            d[0] = f2bf(v.x); d[1] = f2bf(v.y); d[2] = f2bf(v.z); d[3] = f2bf(v.w);
        }
        if (c8 == 0) {
            const float* crow = ct + (size_t)grow * NF_;
            for (int m = 0; m < NF_; m++) A[r * ALD + ED_ + m] = f2bf(crow[m]);
            for (int m = NF_; m < 32; m++) A[r * ALD + ED_ + m] = 0;
        }
    }
    __syncthreads();
    int lane = tid & 63, w = tid >> 6;
    int ncol = nb * 64 + w * 16 + (lane & 15);   // global gate row
    int kb = (lane >> 4) * 8;
    f32x4 acc0 = {0.f,0.f,0.f,0.f}, acc1 = {0.f,0.f,0.f,0.f};
    #pragma unroll
    for (int ks = 0; ks < 9; ks++) {
        int k0 = ks * 32 + kb;
        short8 bfr = *(const short8*)(wb + (size_t)ncol * KP_ + k0);
        short8 a0 = *(const short8*)&A[(lane & 15) * ALD + k0];
        short8 a1 = *(const short8*)&A[(16 + (lane & 15)) * ALD + k0];
        acc0 = __builtin_amdgcn_mfma_f32_16x16x32_bf16(a0, bfr, acc0, 0, 0, 0);
        acc1 = __builtin_amdgcn_mfma_f32_16x16x32_bf16(a1, bfr, acc1, 0, 0, 0);
    }
    float bias = bih0[ncol] + bhh0[ncol];
    #pragma unroll
    for (int r = 0; r < 4; r++) {
        int row0 = (lane >> 4) * 4 + r;
        G0[(size_t)(rbase + row0) * G4H + ncol]      = acc0[r] + bias;
        G0[(size_t)(rbase + 16 + row0) * G4H + ncol] = acc1[r] + bias;
    }
}

// ---------------- persistent 2-layer LSTM scan ----------------
// 64 blocks x 256 threads. Block p owns units [8p, 8p+8) of each layer.
// Weight B-fragments live in VGPRs. h exchanged via global bf16 double buffers.
// Pipelined: iteration it computes L0 step it and L1 step it-1 (1 barrier/iter).
__global__ __launch_bounds__(256, 1) void scan_kernel(
    const float* __restrict__ G0,
    const float* __restrict__ Whh0,
    const float* __restrict__ Wih1, const float* __restrict__ Whh1,
    const float* __restrict__ bih1, const float* __restrict__ bhh1,
    const float* __restrict__ init_c,
    unsigned short* __restrict__ h0buf, unsigned short* __restrict__ h1buf,
    float* __restrict__ lstm_out,
    unsigned* __restrict__ bar)
{
    __shared__ unsigned short h0st[32 * HP];   // 33280 B
    __shared__ float g0l[32 * 33];             // 4224 B
    __shared__ float g1l[32 * 33];             // 4224 B
    __shared__ float c0s[8 * 33];
    __shared__ float c1s[8 * 33];
    __shared__ float bias1[32];

    int tid = threadIdx.x;
    int p = blockIdx.x;                        // 0..63
    int lane = tid & 63, w = tid >> 6;
    int mt = w & 1, nt = w >> 1;
    int lr = nt * 16 + (lane & 15);            // local gate col 0..31
    int gr = (lr >> 3) * H_ + p * 8 + (lr & 7);// global gate row
    int kb = (lane >> 4) * 8;

    // preload weight fragments into registers (192 VGPRs)
    short8 B0[16], B1[32];
    #pragma unroll
    for (int ks = 0; ks < 16; ks++) {
        const float* s0 = Whh0 + (size_t)gr * H_ + ks * 32 + kb;
        const float* s1 = Wih1 + (size_t)gr * H_ + ks * 32 + kb;
        const float* s2 = Whh1 + (size_t)gr * H_ + ks * 32 + kb;
        float4 a = *(const float4*)(s0), b = *(const float4*)(s0 + 4);
        short8 t0; t0[0]=f2bf(a.x);t0[1]=f2bf(a.y);t0[2]=f2bf(a.z);t0[3]=f2bf(a.w);
                   t0[4]=f2bf(b.x);t0[5]=f2bf(b.y);t0[6]=f2bf(b.z);t0[7]=f2bf(b.w);
        B0[ks] = t0;
        a = *(const float4*)(s1); b = *(const float4*)(s1 + 4);
        short8 t1; t1[0]=f2bf(a.x);t1[1]=f2bf(a.y);t1[2]=f2bf(a.z);t1[3]=f2bf(a.w);
                   t1[4]=f2bf(b.x);t1[5]=f2bf(b.y);t1[6]=f2bf(b.z);t1[7]=f2bf(b.w);
        B1[ks] = t1;
        a = *(const float4*)(s2); b = *(const float4*)(s2 + 4);
        short8 t2; t2[0]=f2bf(a.x);t2[1]=f2bf(a.y);t2[2]=f2bf(a.z);t2[3]=f2bf(a.w);
                   t2[4]=f2bf(b.x);t2[5]=f2bf(b.y);t2[6]=f2bf(b.z);t2[7]=f2bf(b.w);
        B1[16 + ks] = t2;
    }
    if (tid < 32) {
        int g = (tid >> 3) * H_ + p * 8 + (tid & 7);
        bias1[tid] = bih1[g] + bhh1[g];
    }
    int uu = tid & 7, b8 = tid >> 3;
    c0s[uu * 33 + b8] = init_c[(size_t)b8 * H_ + p * 8 + uu];
    c1s[uu * 33 + b8] = init_c[(size_t)B_ * H_ + (size_t)b8 * H_ + p * 8 + uu];
    __syncthreads();

    unsigned bar_target = 0;
    for (int it = 0; it <= S_; it++) {
        // stage h0 state[it] into LDS (used by L0 recurrent AND as L1 input x)
        {
            int r = tid >> 3, c8 = tid & 7;
            const unsigned short* s0 = h0buf + (size_t)(it & 1) * (B_ * H_) + (size_t)r * H_;
            #pragma unroll
            for (int jj = 0; jj < 8; jj++) {
                int ch = c8 + 8 * jj;
                *(int4*)&h0st[r * HP + ch * 8] = *(const int4*)(s0 + ch * 8);
            }
        }
        // prefetch G0[t] gate biases for epilogue
        float gpre0 = 0.f, gpre1 = 0.f, gpre2 = 0.f, gpre3 = 0.f;
        if (it < S_) {
            const float* gsrc = G0 + (size_t)(b8 * S_ + it) * G4H + p * 8 + uu;
            gpre0 = gsrc[0]; gpre1 = gsrc[H_]; gpre2 = gsrc[2 * H_]; gpre3 = gsrc[3 * H_];
        }
        __syncthreads();

        f32x4 acc0 = {0.f,0.f,0.f,0.f}, acc1 = {0.f,0.f,0.f,0.f};
        int ar = (mt * 16 + (lane & 15)) * HP;
        #pragma unroll
        for (int ks = 0; ks < 16; ks++) {
            short8 a0 = *(const short8*)&h0st[ar + ks * 32 + kb];
            acc0 = __builtin_amdgcn_mfma_f32_16x16x32_bf16(a0, B0[ks], acc0, 0, 0, 0);
            acc1 = __builtin_amdgcn_mfma_f32_16x16x32_bf16(a0, B1[ks], acc1, 0, 0, 0);
        }
        {   // h1 state[it-1] A-frags straight from global (keeps LDS < 64 KB)
            const unsigned short* h1src = h1buf + (size_t)((it + 1) & 1) * (B_ * H_)
                                        + (size_t)(mt * 16 + (lane & 15)) * H_ + kb;
            #pragma unroll
            for (int ks = 0; ks < 16; ks++) {
                short8 a1 = *(const short8*)(h1src + ks * 32);
                acc1 = __builtin_amdgcn_mfma_f32_16x16x32_bf16(a1, B1[16 + ks], acc1, 0, 0, 0);
            }
        }
        #pragma unroll
        for (int r = 0; r < 4; r++) {
            int row = mt * 16 + (lane >> 4) * 4 + r;
            g0l[row * 33 + lr] = acc0[r];
            g1l[row * 33 + lr] = acc1[r];
        }
        __syncthreads();

        if (it < S_) {
            float iv = g0l[b8 * 33 + uu]       + gpre0;
            float fv = g0l[b8 * 33 + 8 + uu]   + gpre1;
            float gv = g0l[b8 * 33 + 16 + uu]  + gpre2;
            float ov = g0l[b8 * 33 + 24 + uu]  + gpre3;
            float c = c0s[uu * 33 + b8];
            c = sigf(fv) * c + sigf(iv) * tanhf(gv);
            c0s[uu * 33 + b8] = c;
            float h = sigf(ov) * tanhf(c);
            h0buf[(size_t)((it + 1) & 1) * (B_ * H_) + (size_t)b8 * H_ + p * 8 + uu] = f2bf(h);
        }
        if (it >= 1) {
            float iv = g1l[b8 * 33 + uu]       + bias1[uu];
            float fv = g1l[b8 * 33 + 8 + uu]   + bias1[8 + uu];
            float gv = g1l[b8 * 33 + 16 + uu]  + bias1[16 + uu];
            float ov = g1l[b8 * 33 + 24 + uu]  + bias1[24 + uu];
            float c = c1s[uu * 33 + b8];
            c = sigf(fv) * c + sigf(iv) * tanhf(gv);
            c1s[uu * 33 + b8] = c;
            float h = sigf(ov) * tanhf(c);
            h1buf[(size_t)(it & 1) * (B_ * H_) + (size_t)b8 * H_ + p * 8 + uu] = f2bf(h);
            lstm_out[(size_t)(b8 * S_ + (it - 1)) * H_ + p * 8 + uu] = h;
        }

        // grid barrier (device-scope, all 64 blocks co-resident)
        bar_target += 64;
        __syncthreads();
        if (tid == 0) {
            __threadfence();
            atomicAdd(bar, 1u);
            while (__hip_atomic_load(bar, __ATOMIC_RELAXED, __HIP_MEMORY_SCOPE_AGENT) < bar_target) {
                __builtin_amdgcn_s_sleep(1);
            }
            __threadfence();
        }
        __syncthreads();
    }
}

// ---------------- gathered prediction + BCE ----------------
__global__ __launch_bounds__(256) void pred_kernel(
    const float* __restrict__ lstm_out, const float* __restrict__ cn,
    const float* __restrict__ Wp, const float* __restrict__ bp,
    const int* __restrict__ qt, const float* __restrict__ target,
    float* __restrict__ out, float* __restrict__ accum)
{
    int wv = (blockIdx.x * 256 + threadIdx.x) >> 6;   // one wave per row
    int lane = threadIdx.x & 63;
    if (wv >= NROW) return;
    int q = qt[wv];
    const float* wrow = Wp + (size_t)q * (H_ + NF_);
    const float* hrow = lstm_out + (size_t)wv * H_;
    float part = 0.f;
    #pragma unroll
    for (int i = 0; i < H_ / 64; i++) part += hrow[lane + i * 64] * wrow[lane + i * 64];
    if (lane < NF_) part += cn[(size_t)wv * NF_ + lane] * wrow[H_ + lane];
    #pragma unroll
    for (int off = 32; off; off >>= 1) part += __shfl_down(part, off, 64);
    if (lane == 0) {
        float x = part + bp[q];
        float t = target[wv];
        float mask = (q > 0) ? 1.f : 0.f;
        out[1 + wv] = mask / (1.f + __expf(-x));
        out[1 + NROW + wv] = t * mask;
        float bce = fmaxf(x, 0.f) - x * t + log1pf(__expf(-fabsf(x)));
        atomicAdd(&accum[0], bce * mask);
        atomicAdd(&accum[1], mask);
    }
}

__global__ void final_kernel(const float* __restrict__ accum, float* __restrict__ out)
{
    out[0] = accum[0] / accum[1];
}

extern "C" void kernel_launch(void* const* d_in, const int* in_sizes, int n_in,
                              void* d_out, int out_size, void* d_ws, size_t ws_size,
                              hipStream_t stream)
{
    (void)in_sizes; (void)n_in; (void)out_size; (void)ws_size;
    const int*   x_data = (const int*)  d_in[0];
    const int*   q_t    = (const int*)  d_in[1];
    const float* target = (const float*)d_in[2];
    const float* rep    = (const float*)d_in[3];
    const float* past   = (const float*)d_in[4];
    const float* seq    = (const float*)d_in[5];
    const float* embed  = (const float*)d_in[6];
    const float* Wih0   = (const float*)d_in[7];
    const float* Whh0   = (const float*)d_in[8];
    const float* bih0   = (const float*)d_in[9];
    const float* bhh0   = (const float*)d_in[10];
    const float* Wih1   = (const float*)d_in[11];
    const float* Whh1   = (const float*)d_in[12];
    const float* bih1   = (const float*)d_in[13];
    const float* bhh1   = (const float*)d_in[14];
    const float* Wp     = (const float*)d_in[15];
    const float* bp     = (const float*)d_in[16];
    const float* C      = (const float*)d_in[17];
    const float* init_h = (const float*)d_in[18];
    const float* init_c = (const float*)d_in[19];

    char* ws = (char*)d_ws;
    float*          G0    = (float*)         (ws + OFF_G0);
    float*          lstm  = (float*)         (ws + OFF_LSTM);
    float*          ct    = (float*)         (ws + OFF_CT);
    float*          cn    = (float*)         (ws + OFF_CN);
    unsigned short* h0buf = (unsigned short*)(ws + OFF_H0);
    unsigned short* h1buf = (unsigned short*)(ws + OFF_H1);
    unsigned*       sync  = (unsigned*)      (ws + OFF_SYNC);
    unsigned short* wb    = (unsigned short*)(ws + OFF_WB);
    float* out = (float*)d_out;

    prep_kernel<<<540, 256, 0, stream>>>(C, rep, past, seq, init_h, ct, cn, h0buf, h1buf, sync);
    prepw_kernel<<<(G4H * KP_ + 255) / 256, 256, 0, stream>>>(Wih0, wb);
    g0_kernel<<<6400, 256, 0, stream>>>(x_data, embed, wb, bih0, bhh0, ct, G0);
    scan_kernel<<<64, 256, 0, stream>>>(G0, Whh0, Wih1, Whh1, bih1, bhh1, init_c,
                                        h0buf, h1buf, lstm, sync);
    pred_kernel<<<NROW / 4, 256, 0, stream>>>(lstm, cn, Wp, bp, q_t, target, out,
                                              (float*)(sync + 1));
    final_kernel<<<1, 1, 0, stream>>>((const float*)(sync + 1), out);
}

// Round 2
// 2351.706 us; speedup vs baseline: 1.1184x; 1.1184x over previous
//
#include <hip/hip_runtime.h>
#include <hip/hip_bf16.h>

#define B_   32
#define S_   200
#define H_   512
#define ED_  256
#define NF_  19
#define NROW (B_*S_)      // 6400
#define G4H  (4*H_)       // 2048
#define KIN  (ED_+NF_)    // 275
#define KP_  288          // padded K for input GEMM
#define ALD  296          // A-tile LDS row stride (bf16)
#define HP   520          // h-stage LDS row stride (bf16)

typedef __attribute__((ext_vector_type(8))) short short8;
typedef __attribute__((ext_vector_type(4))) float f32x4;
typedef union { unsigned long long u[2]; short8 s8; } cvt8;

// ---------------- workspace layout (bytes) ----------------
#define OFF_G0   0ull
#define SZ_G0    ((size_t)NROW*G4H*4)            // 52428800
#define OFF_LSTM (OFF_G0 + SZ_G0)
#define SZ_LSTM  ((size_t)NROW*H_*4)             // 13107200
#define OFF_CT   (OFF_LSTM + SZ_LSTM)
#define SZ_CT    ((size_t)NROW*NF_*4)            // 486400
#define OFF_CN   (OFF_CT + SZ_CT)
#define OFF_H0   (OFF_CN + SZ_CT)
#define SZ_HB    ((size_t)2*B_*H_*2)             // 65536 (bf16 double buffer)
#define OFF_H1   (OFF_H0 + SZ_HB)
#define OFF_SYNC (OFF_H1 + SZ_HB)                // [0]=barrier u32, [1]=num f32, [2]=den f32
#define OFF_WB   (OFF_SYNC + 256)                // Wih0 pre-converted bf16 [2048][288]
#define SZ_WB    ((size_t)G4H*KP_*2)             // 1179648

__device__ __forceinline__ unsigned short f2bf(float f) {
    unsigned u = __float_as_uint(f);
    unsigned r = u + 0x7fffu + ((u >> 16) & 1u);
    return (unsigned short)(r >> 16);
}
__device__ __forceinline__ float sigf(float x) { return 1.0f / (1.0f + __expf(-x)); }

__device__ __forceinline__ unsigned long long aload64(const unsigned short* p) {
    return __hip_atomic_load((const unsigned long long*)p, __ATOMIC_RELAXED,
                             __HIP_MEMORY_SCOPE_AGENT);
}

// ---------------- prep: c_t/c_next, h-buffer init, sync zero ----------------
__global__ __launch_bounds__(256) void prep_kernel(
    const float* __restrict__ C, const float* __restrict__ rep,
    const float* __restrict__ past, const float* __restrict__ seq,
    const float* __restrict__ init_h,
    float* __restrict__ ct, float* __restrict__ cn,
    unsigned short* __restrict__ h0buf, unsigned short* __restrict__ h1buf,
    unsigned* __restrict__ syncbuf)
{
    int idx = blockIdx.x * 256 + threadIdx.x;
    if (idx < NROW * NF_) {
        int m = idx % NF_; int row = idx / NF_;
        int b = row / S_, s = row % S_;
        float cc = C[idx];
        float v0, v1;
        if (m < 7)       { v0 = rep [(b*(S_+1)+s)*7 + m];      v1 = rep [(b*(S_+1)+s+1)*7 + m]; }
        else if (m < 13) { v0 = seq [(b*(S_+1)+s)*6 + (m-7)];  v1 = seq [(b*(S_+1)+s+1)*6 + (m-7)]; }
        else             { v0 = past[(b*(S_+1)+s)*6 + (m-13)]; v1 = past[(b*(S_+1)+s+1)*6 + (m-13)]; }
        ct[idx] = cc * v0;
        cn[idx] = cc * v1;
    }
    int j = idx - NROW * NF_;
    if (j >= 0 && j < B_ * H_) {
        h0buf[j] = f2bf(init_h[j]);
        h1buf[j] = f2bf(init_h[B_ * H_ + j]);
    }
    if (j >= B_ * H_ && j < B_ * H_ + 4) syncbuf[j - B_ * H_] = 0u;
}

// ---------------- prep_w: Wih0 f32[2048][275] -> bf16[2048][288] (zero-pad) ----------------
__global__ __launch_bounds__(256) void prepw_kernel(
    const float* __restrict__ Wih0, unsigned short* __restrict__ wb)
{
    int idx = blockIdx.x * 256 + threadIdx.x;
    if (idx >= G4H * KP_) return;
    int k = idx % KP_; int r = idx / KP_;
    wb[idx] = (k < KIN) ? f2bf(Wih0[(size_t)r * KIN + k]) : (unsigned short)0;
}

// ---------------- G0 = [emb|c_t] @ Wih0^T + bih0 + bhh0  (bf16 MFMA) ----------------
__global__ __launch_bounds__(256) void g0_kernel(
    const int* __restrict__ x_data, const float* __restrict__ embed,
    const unsigned short* __restrict__ wb,
    const float* __restrict__ bih0, const float* __restrict__ bhh0,
    const float* __restrict__ ct, float* __restrict__ G0)
{
    __shared__ unsigned short A[32 * ALD];
    int tid = threadIdx.x;
    int bx = blockIdx.x;
    int mb = bx >> 5;          // 0..199  (row tile of 32)
    int nb = bx & 31;          // 0..31   (col tile of 64)
    int rbase = mb * 32;
    {   // stage A: 32 gathered rows of [emb(256)|c_t(19)|pad]
        int r = tid >> 3, c8 = tid & 7;
        int grow = rbase + r;
        const float* erow = embed + (size_t)x_data[grow] * ED_;
        #pragma unroll
        for (int jj = 0; jj < 8; jj++) {
            float4 v = *(const float4*)(erow + c8 * 32 + jj * 4);
            unsigned short* d = &A[r * ALD + c8 * 32 + jj * 4];
            d[0] = f2bf(v.x); d[1] = f2bf(v.y); d[2] = f2bf(v.z); d[3] = f2bf(v.w);
        }
        if (c8 == 0) {
            const float* crow = ct + (size_t)grow * NF_;
            for (int m = 0; m < NF_; m++) A[r * ALD + ED_ + m] = f2bf(crow[m]);
            for (int m = NF_; m < 32; m++) A[r * ALD + ED_ + m] = 0;
        }
    }
    __syncthreads();
    int lane = tid & 63, w = tid >> 6;
    int ncol = nb * 64 + w * 16 + (lane & 15);   // global gate row
    int kb = (lane >> 4) * 8;
    f32x4 acc0 = {0.f,0.f,0.f,0.f}, acc1 = {0.f,0.f,0.f,0.f};
    #pragma unroll
    for (int ks = 0; ks < 9; ks++) {
        int k0 = ks * 32 + kb;
        short8 bfr = *(const short8*)(wb + (size_t)ncol * KP_ + k0);
        short8 a0 = *(const short8*)&A[(lane & 15) * ALD + k0];
        short8 a1 = *(const short8*)&A[(16 + (lane & 15)) * ALD + k0];
        acc0 = __builtin_amdgcn_mfma_f32_16x16x32_bf16(a0, bfr, acc0, 0, 0, 0);
        acc1 = __builtin_amdgcn_mfma_f32_16x16x32_bf16(a1, bfr, acc1, 0, 0, 0);
    }
    float bias = bih0[ncol] + bhh0[ncol];
    #pragma unroll
    for (int r = 0; r < 4; r++) {
        int row0 = (lane >> 4) * 4 + r;
        G0[(size_t)(rbase + row0) * G4H + ncol]      = acc0[r] + bias;
        G0[(size_t)(rbase + 16 + row0) * G4H + ncol] = acc1[r] + bias;
    }
}

// ---------------- persistent 2-layer LSTM scan ----------------
// 64 blocks x 256 threads. Block p owns units [8p, 8p+8) of each layer.
// Weight B-fragments live in VGPRs. h exchanged via global bf16 double buffers
// using per-access coherent (sc0/sc1) relaxed agent-scope atomics — NO fences,
// NO L2 writeback/invalidate. Ordering: s_waitcnt vmcnt(0) in every wave
// before the barrier arrive; control dependency on the spin load after.
__global__ __launch_bounds__(256, 1) void scan_kernel(
    const float* __restrict__ G0,
    const float* __restrict__ Whh0,
    const float* __restrict__ Wih1, const float* __restrict__ Whh1,
    const float* __restrict__ bih1, const float* __restrict__ bhh1,
    const float* __restrict__ init_c,
    unsigned short* __restrict__ h0buf, unsigned short* __restrict__ h1buf,
    float* __restrict__ lstm_out,
    unsigned* __restrict__ bar)
{
    __shared__ unsigned short h0st[32 * HP];   // 33280 B
    __shared__ float g0l[32 * 33];             // 4224 B
    __shared__ float g1l[32 * 33];             // 4224 B
    __shared__ float c0s[8 * 33];
    __shared__ float c1s[8 * 33];
    __shared__ float bias1[32];

    int tid = threadIdx.x;
    int p = blockIdx.x;                        // 0..63
    int lane = tid & 63, w = tid >> 6;
    int mt = w & 1, nt = w >> 1;
    int lr = nt * 16 + (lane & 15);            // local gate col 0..31
    int gr = (lr >> 3) * H_ + p * 8 + (lr & 7);// global gate row
    int kb = (lane >> 4) * 8;

    // preload weight fragments into registers (192 VGPRs)
    short8 B0[16], B1[32];
    #pragma unroll
    for (int ks = 0; ks < 16; ks++) {
        const float* s0 = Whh0 + (size_t)gr * H_ + ks * 32 + kb;
        const float* s1 = Wih1 + (size_t)gr * H_ + ks * 32 + kb;
        const float* s2 = Whh1 + (size_t)gr * H_ + ks * 32 + kb;
        float4 a = *(const float4*)(s0), b = *(const float4*)(s0 + 4);
        short8 t0; t0[0]=f2bf(a.x);t0[1]=f2bf(a.y);t0[2]=f2bf(a.z);t0[3]=f2bf(a.w);
                   t0[4]=f2bf(b.x);t0[5]=f2bf(b.y);t0[6]=f2bf(b.z);t0[7]=f2bf(b.w);
        B0[ks] = t0;
        a = *(const float4*)(s1); b = *(const float4*)(s1 + 4);
        short8 t1; t1[0]=f2bf(a.x);t1[1]=f2bf(a.y);t1[2]=f2bf(a.z);t1[3]=f2bf(a.w);
                   t1[4]=f2bf(b.x);t1[5]=f2bf(b.y);t1[6]=f2bf(b.z);t1[7]=f2bf(b.w);
        B1[ks] = t1;
        a = *(const float4*)(s2); b = *(const float4*)(s2 + 4);
        short8 t2; t2[0]=f2bf(a.x);t2[1]=f2bf(a.y);t2[2]=f2bf(a.z);t2[3]=f2bf(a.w);
                   t2[4]=f2bf(b.x);t2[5]=f2bf(b.y);t2[6]=f2bf(b.z);t2[7]=f2bf(b.w);
        B1[16 + ks] = t2;
    }
    if (tid < 32) {
        int g = (tid >> 3) * H_ + p * 8 + (tid & 7);
        bias1[tid] = bih1[g] + bhh1[g];
    }
    int uu = tid & 7, b8 = tid >> 3;
    c0s[uu * 33 + b8] = init_c[(size_t)b8 * H_ + p * 8 + uu];
    c1s[uu * 33 + b8] = init_c[(size_t)B_ * H_ + (size_t)b8 * H_ + p * 8 + uu];
    __syncthreads();

    unsigned bar_target = 0;
    for (int it = 0; it <= S_; it++) {
        // stage h0 state[it] into LDS via coherent u64 loads
        {
            int r = tid >> 3, c8 = tid & 7;
            const unsigned short* s0 = h0buf + (size_t)(it & 1) * (B_ * H_) + (size_t)r * H_;
            #pragma unroll
            for (int jj = 0; jj < 16; jj++) {
                int ch = c8 + 8 * jj;                    // u64 chunk 0..127
                unsigned long long v = aload64(s0 + ch * 4);
                *(unsigned long long*)&h0st[r * HP + ch * 4] = v;
            }
        }
        // prefetch G0[t] gate biases for epilogue (independent of h)
        float gpre0 = 0.f, gpre1 = 0.f, gpre2 = 0.f, gpre3 = 0.f;
        if (it < S_) {
            const float* gsrc = G0 + (size_t)(b8 * S_ + it) * G4H + p * 8 + uu;
            gpre0 = gsrc[0]; gpre1 = gsrc[H_]; gpre2 = gsrc[2 * H_]; gpre3 = gsrc[3 * H_];
        }
        __syncthreads();

        f32x4 acc0 = {0.f,0.f,0.f,0.f}, acc1 = {0.f,0.f,0.f,0.f};
        int ar = (mt * 16 + (lane & 15)) * HP;
        #pragma unroll
        for (int ks = 0; ks < 16; ks++) {
            short8 a0 = *(const short8*)&h0st[ar + ks * 32 + kb];
            acc0 = __builtin_amdgcn_mfma_f32_16x16x32_bf16(a0, B0[ks], acc0, 0, 0, 0);
            acc1 = __builtin_amdgcn_mfma_f32_16x16x32_bf16(a0, B1[ks], acc1, 0, 0, 0);
        }
        {   // h1 state[it-1] A-frags from global via coherent u64 loads
            const unsigned short* h1src = h1buf + (size_t)((it + 1) & 1) * (B_ * H_)
                                        + (size_t)(mt * 16 + (lane & 15)) * H_ + kb;
            #pragma unroll
            for (int ks = 0; ks < 16; ks++) {
                cvt8 cv;
                cv.u[0] = aload64(h1src + ks * 32);
                cv.u[1] = aload64(h1src + ks * 32 + 4);
                acc1 = __builtin_amdgcn_mfma_f32_16x16x32_bf16(cv.s8, B1[16 + ks], acc1, 0, 0, 0);
            }
        }
        #pragma unroll
        for (int r = 0; r < 4; r++) {
            int row = mt * 16 + (lane >> 4) * 4 + r;
            g0l[row * 33 + lr] = acc0[r];
            g1l[row * 33 + lr] = acc1[r];
        }
        __syncthreads();

        if (it < S_) {
            float iv = g0l[b8 * 33 + uu]       + gpre0;
            float fv = g0l[b8 * 33 + 8 + uu]   + gpre1;
            float gv = g0l[b8 * 33 + 16 + uu]  + gpre2;
            float ov = g0l[b8 * 33 + 24 + uu]  + gpre3;
            float c = c0s[uu * 33 + b8];
            c = sigf(fv) * c + sigf(iv) * tanhf(gv);
            c0s[uu * 33 + b8] = c;
            float h = sigf(ov) * tanhf(c);
            unsigned short hb = f2bf(h);
            float hn = __shfl_down(h, 1, 64);          // partner (uu+1) value
            if (!(uu & 1)) {
                unsigned pk = (unsigned)hb | ((unsigned)f2bf(hn) << 16);
                unsigned short* dst = h0buf + (size_t)((it + 1) & 1) * (B_ * H_)
                                    + (size_t)b8 * H_ + p * 8 + uu;
                __hip_atomic_store((unsigned*)dst, pk, __ATOMIC_RELAXED,
                                   __HIP_MEMORY_SCOPE_AGENT);
            }
        }
        if (it >= 1) {
            float iv = g1l[b8 * 33 + uu]       + bias1[uu];
            float fv = g1l[b8 * 33 + 8 + uu]   + bias1[8 + uu];
            float gv = g1l[b8 * 33 + 16 + uu]  + bias1[16 + uu];
            float ov = g1l[b8 * 33 + 24 + uu]  + bias1[24 + uu];
            float c = c1s[uu * 33 + b8];
            c = sigf(fv) * c + sigf(iv) * tanhf(gv);
            c1s[uu * 33 + b8] = c;
            float h = sigf(ov) * tanhf(c);
            unsigned short hb = f2bf(h);
            float hn = __shfl_down(h, 1, 64);
            if (!(uu & 1)) {
                unsigned pk = (unsigned)hb | ((unsigned)f2bf(hn) << 16);
                unsigned short* dst = h1buf + (size_t)(it & 1) * (B_ * H_)
                                    + (size_t)b8 * H_ + p * 8 + uu;
                __hip_atomic_store((unsigned*)dst, pk, __ATOMIC_RELAXED,
                                   __HIP_MEMORY_SCOPE_AGENT);
            }
            lstm_out[(size_t)(b8 * S_ + (it - 1)) * H_ + p * 8 + uu] = h;
        }

        if (it < S_) {
            // grid barrier: every wave drains its own stores to the coherence
            // point, then one lane arrives; spin on relaxed agent load.
            bar_target += 64;
            asm volatile("s_waitcnt vmcnt(0)" ::: "memory");
            __syncthreads();
            if (tid == 0) {
                __hip_atomic_fetch_add(bar, 1u, __ATOMIC_RELAXED, __HIP_MEMORY_SCOPE_AGENT);
                while (__hip_atomic_load(bar, __ATOMIC_RELAXED, __HIP_MEMORY_SCOPE_AGENT) < bar_target) {
                    __builtin_amdgcn_s_sleep(1);
                }
            }
            __syncthreads();
        }
    }
}

// ---------------- gathered prediction + BCE ----------------
__global__ __launch_bounds__(256) void pred_kernel(
    const float* __restrict__ lstm_out, const float* __restrict__ cn,
    const float* __restrict__ Wp, const float* __restrict__ bp,
    const int* __restrict__ qt, const float* __restrict__ target,
    float* __restrict__ out, float* __restrict__ accum)
{
    int wv = (blockIdx.x * 256 + threadIdx.x) >> 6;   // one wave per row
    int lane = threadIdx.x & 63;
    if (wv >= NROW) return;
    int q = qt[wv];
    const float* wrow = Wp + (size_t)q * (H_ + NF_);
    const float* hrow = lstm_out + (size_t)wv * H_;
    float part = 0.f;
    #pragma unroll
    for (int i = 0; i < H_ / 64; i++) part += hrow[lane + i * 64] * wrow[lane + i * 64];
    if (lane < NF_) part += cn[(size_t)wv * NF_ + lane] * wrow[H_ + lane];
    #pragma unroll
    for (int off = 32; off; off >>= 1) part += __shfl_down(part, off, 64);
    if (lane == 0) {
        float x = part + bp[q];
        float t = target[wv];
        float mask = (q > 0) ? 1.f : 0.f;
        out[1 + wv] = mask / (1.f + __expf(-x));
        out[1 + NROW + wv] = t * mask;
        float bce = fmaxf(x, 0.f) - x * t + log1pf(__expf(-fabsf(x)));
        atomicAdd(&accum[0], bce * mask);
        atomicAdd(&accum[1], mask);
    }
}

__global__ void final_kernel(const float* __restrict__ accum, float* __restrict__ out)
{
    out[0] = accum[0] / accum[1];
}

extern "C" void kernel_launch(void* const* d_in, const int* in_sizes, int n_in,
                              void* d_out, int out_size, void* d_ws, size_t ws_size,
                              hipStream_t stream)
{
    (void)in_sizes; (void)n_in; (void)out_size; (void)ws_size;
    const int*   x_data = (const int*)  d_in[0];
    const int*   q_t    = (const int*)  d_in[1];
    const float* target = (const float*)d_in[2];
    const float* rep    = (const float*)d_in[3];
    const float* past   = (const float*)d_in[4];
    const float* seq    = (const float*)d_in[5];
    const float* embed  = (const float*)d_in[6];
    const float* Wih0   = (const float*)d_in[7];
    const float* Whh0   = (const float*)d_in[8];
    const float* bih0   = (const float*)d_in[9];
    const float* bhh0   = (const float*)d_in[10];
    const float* Wih1   = (const float*)d_in[11];
    const float* Whh1   = (const float*)d_in[12];
    const float* bih1   = (const float*)d_in[13];
    const float* bhh1   = (const float*)d_in[14];
    const float* Wp     = (const float*)d_in[15];
    const float* bp     = (const float*)d_in[16];
    const float* C      = (const float*)d_in[17];
    const float* init_h = (const float*)d_in[18];
    const float* init_c = (const float*)d_in[19];

    char* ws = (char*)d_ws;
    float*          G0    = (float*)         (ws + OFF_G0);
    float*          lstm  = (float*)         (ws + OFF_LSTM);
    float*          ct    = (float*)         (ws + OFF_CT);
    float*          cn    = (float*)         (ws + OFF_CN);
    unsigned short* h0buf = (unsigned short*)(ws + OFF_H0);
    unsigned short* h1buf = (unsigned short*)(ws + OFF_H1);
    unsigned*       sync  = (unsigned*)      (ws + OFF_SYNC);
    unsigned short* wb    = (unsigned short*)(ws + OFF_WB);
    float* out = (float*)d_out;

    prep_kernel<<<540, 256, 0, stream>>>(C, rep, past, seq, init_h, ct, cn, h0buf, h1buf, sync);
    prepw_kernel<<<(G4H * KP_ + 255) / 256, 256, 0, stream>>>(Wih0, wb);
    g0_kernel<<<6400, 256, 0, stream>>>(x_data, embed, wb, bih0, bhh0, ct, G0);
    scan_kernel<<<64, 256, 0, stream>>>(G0, Whh0, Wih1, Whh1, bih1, bhh1, init_c,
                                        h0buf, h1buf, lstm, sync);
    pred_kernel<<<NROW / 4, 256, 0, stream>>>(lstm, cn, Wp, bp, q_t, target, out,
                                              (float*)(sync + 1));
    final_kernel<<<1, 1, 0, stream>>>((const float*)(sync + 1), out);
}

// Round 3
// 1734.275 us; speedup vs baseline: 1.5166x; 1.3560x over previous
//
#include <hip/hip_runtime.h>
#include <hip/hip_bf16.h>

#define B_   32
#define S_   200
#define H_   512
#define ED_  256
#define NF_  19
#define NROW (B_*S_)      // 6400
#define G4H  (4*H_)       // 2048
#define KIN  (ED_+NF_)    // 275
#define KP_  288          // padded K for input GEMM
#define ALD  296          // A-tile LDS row stride (bf16)

typedef __attribute__((ext_vector_type(8))) short short8;
typedef __attribute__((ext_vector_type(4))) float f32x4;

// ---------------- workspace layout (bytes) ----------------
#define OFF_G0   0ull
#define SZ_G0    ((size_t)NROW*G4H*4)            // 52428800
#define OFF_LSTM (OFF_G0 + SZ_G0)
#define SZ_LSTM  ((size_t)NROW*H_*4)             // 13107200
#define OFF_CT   (OFF_LSTM + SZ_LSTM)
#define SZ_CT    ((size_t)NROW*NF_*4)            // 486400
#define OFF_CN   (OFF_CT + SZ_CT)
#define OFF_H0   (OFF_CN + SZ_CT)
#define SZ_HB    ((size_t)2*B_*H_*2)             // 65536 (bf16 double buffer)
#define OFF_H1   (OFF_H0 + SZ_HB)
#define OFF_SYNC (OFF_H1 + SZ_HB)                // [0]=barrier u32, [1]=num f32, [2]=den f32
#define OFF_WB   (OFF_SYNC + 256)                // Wih0 pre-converted bf16 [2048][288]
#define SZ_WB    ((size_t)G4H*KP_*2)             // 1179648

__device__ __forceinline__ unsigned short f2bf(float f) {
    unsigned u = __float_as_uint(f);
    unsigned r = u + 0x7fffu + ((u >> 16) & 1u);
    return (unsigned short)(r >> 16);
}
__device__ __forceinline__ float sigf(float x) { return 1.0f / (1.0f + __expf(-x)); }

// coherent (agent-scope) 16B load, bypasses L1/L2, served at the MALL
#define CLD16(d, p, o) \
    asm volatile("global_load_dwordx4 %0, %1, off offset:" o " sc0 sc1" \
                 : "=v"(d) : "v"(p))
#define CLDALL(F, p) do { \
    CLD16(F[0],p,"0");   CLD16(F[1],p,"64");  CLD16(F[2],p,"128"); CLD16(F[3],p,"192"); \
    CLD16(F[4],p,"256"); CLD16(F[5],p,"320"); CLD16(F[6],p,"384"); CLD16(F[7],p,"448"); \
    CLD16(F[8],p,"512"); CLD16(F[9],p,"576"); CLD16(F[10],p,"640");CLD16(F[11],p,"704"); \
    CLD16(F[12],p,"768");CLD16(F[13],p,"832");CLD16(F[14],p,"896");CLD16(F[15],p,"960"); \
} while (0)
// coherent 4B store
#define CST32(a, v) \
    asm volatile("global_store_dword %0, %1, off sc0 sc1" :: "v"(a), "v"(v) : "memory")

// ---------------- prep: c_t/c_next, h-buffer init, sync zero ----------------
__global__ __launch_bounds__(256) void prep_kernel(
    const float* __restrict__ C, const float* __restrict__ rep,
    const float* __restrict__ past, const float* __restrict__ seq,
    const float* __restrict__ init_h,
    float* __restrict__ ct, float* __restrict__ cn,
    unsigned short* __restrict__ h0buf, unsigned short* __restrict__ h1buf,
    unsigned* __restrict__ syncbuf)
{
    int idx = blockIdx.x * 256 + threadIdx.x;
    if (idx < NROW * NF_) {
        int m = idx % NF_; int row = idx / NF_;
        int b = row / S_, s = row % S_;
        float cc = C[idx];
        float v0, v1;
        if (m < 7)       { v0 = rep [(b*(S_+1)+s)*7 + m];      v1 = rep [(b*(S_+1)+s+1)*7 + m]; }
        else if (m < 13) { v0 = seq [(b*(S_+1)+s)*6 + (m-7)];  v1 = seq [(b*(S_+1)+s+1)*6 + (m-7)]; }
        else             { v0 = past[(b*(S_+1)+s)*6 + (m-13)]; v1 = past[(b*(S_+1)+s+1)*6 + (m-13)]; }
        ct[idx] = cc * v0;
        cn[idx] = cc * v1;
    }
    int j = idx - NROW * NF_;
    if (j >= 0 && j < B_ * H_) {
        h0buf[j] = f2bf(init_h[j]);
        h1buf[j] = f2bf(init_h[B_ * H_ + j]);
    }
    if (j >= B_ * H_ && j < B_ * H_ + 4) syncbuf[j - B_ * H_] = 0u;
}

// ---------------- prep_w: Wih0 f32[2048][275] -> bf16[2048][288] (zero-pad) ----------------
__global__ __launch_bounds__(256) void prepw_kernel(
    const float* __restrict__ Wih0, unsigned short* __restrict__ wb)
{
    int idx = blockIdx.x * 256 + threadIdx.x;
    if (idx >= G4H * KP_) return;
    int k = idx % KP_; int r = idx / KP_;
    wb[idx] = (k < KIN) ? f2bf(Wih0[(size_t)r * KIN + k]) : (unsigned short)0;
}

// ---------------- G0 = [emb|c_t] @ Wih0^T + bih0 + bhh0  (bf16 MFMA) ----------------
__global__ __launch_bounds__(256) void g0_kernel(
    const int* __restrict__ x_data, const float* __restrict__ embed,
    const unsigned short* __restrict__ wb,
    const float* __restrict__ bih0, const float* __restrict__ bhh0,
    const float* __restrict__ ct, float* __restrict__ G0)
{
    __shared__ unsigned short A[32 * ALD];
    int tid = threadIdx.x;
    int bx = blockIdx.x;
    int mb = bx >> 5;          // 0..199  (row tile of 32)
    int nb = bx & 31;          // 0..31   (col tile of 64)
    int rbase = mb * 32;
    {   // stage A: 32 gathered rows of [emb(256)|c_t(19)|pad]
        int r = tid >> 3, c8 = tid & 7;
        int grow = rbase + r;
        const float* erow = embed + (size_t)x_data[grow] * ED_;
        #pragma unroll
        for (int jj = 0; jj < 8; jj++) {
            float4 v = *(const float4*)(erow + c8 * 32 + jj * 4);
            unsigned short* d = &A[r * ALD + c8 * 32 + jj * 4];
            d[0] = f2bf(v.x); d[1] = f2bf(v.y); d[2] = f2bf(v.z); d[3] = f2bf(v.w);
        }
        if (c8 == 0) {
            const float* crow = ct + (size_t)grow * NF_;
            for (int m = 0; m < NF_; m++) A[r * ALD + ED_ + m] = f2bf(crow[m]);
            for (int m = NF_; m < 32; m++) A[r * ALD + ED_ + m] = 0;
        }
    }
    __syncthreads();
    int lane = tid & 63, w = tid >> 6;
    int ncol = nb * 64 + w * 16 + (lane & 15);   // global gate row
    int kb = (lane >> 4) * 8;
    f32x4 acc0 = {0.f,0.f,0.f,0.f}, acc1 = {0.f,0.f,0.f,0.f};
    #pragma unroll
    for (int ks = 0; ks < 9; ks++) {
        int k0 = ks * 32 + kb;
        short8 bfr = *(const short8*)(wb + (size_t)ncol * KP_ + k0);
        short8 a0 = *(const short8*)&A[(lane & 15) * ALD + k0];
        short8 a1 = *(const short8*)&A[(16 + (lane & 15)) * ALD + k0];
        acc0 = __builtin_amdgcn_mfma_f32_16x16x32_bf16(a0, bfr, acc0, 0, 0, 0);
        acc1 = __builtin_amdgcn_mfma_f32_16x16x32_bf16(a1, bfr, acc1, 0, 0, 0);
    }
    float bias = bih0[ncol] + bhh0[ncol];
    #pragma unroll
    for (int r = 0; r < 4; r++) {
        int row0 = (lane >> 4) * 4 + r;
        G0[(size_t)(rbase + row0) * G4H + ncol]      = acc0[r] + bias;
        G0[(size_t)(rbase + 16 + row0) * G4H + ncol] = acc1[r] + bias;
    }
}

// ---------------- persistent 2-layer LSTM scan ----------------
// 64 blocks x 256 threads. Block p owns units [8p, 8p+8) of each layer.
// Weights stationary in VGPRs. h exchanged through global bf16 double buffers
// with per-access coherent (sc0 sc1) ops — no fences, no L2 flush.
// Per iteration: ONE wide pipelined coherent-load burst direct to MFMA
// fragments (no LDS staging phase), MFMA (3 parallel 16-chains), LDS gate
// exchange, epilogue, coherent stores, single vmcnt drain, counter barrier.
__global__ __launch_bounds__(256, 1) void scan_kernel(
    const float* __restrict__ G0,
    const float* __restrict__ Whh0,
    const float* __restrict__ Wih1, const float* __restrict__ Whh1,
    const float* __restrict__ bih1, const float* __restrict__ bhh1,
    const float* __restrict__ init_c,
    unsigned short* __restrict__ h0buf, unsigned short* __restrict__ h1buf,
    float* __restrict__ lstm_out,
    unsigned* __restrict__ bar)
{
    __shared__ float g0l[32 * 33];             // 4224 B
    __shared__ float g1l[32 * 33];             // 4224 B
    __shared__ float c0s[8 * 33];
    __shared__ float c1s[8 * 33];
    __shared__ float bias1[32];

    int tid = threadIdx.x;
    int p = blockIdx.x;                        // 0..63
    int lane = tid & 63, w = tid >> 6;
    int mt = w & 1, nt = w >> 1;
    int lr = nt * 16 + (lane & 15);            // local gate col 0..31
    int gr = (lr >> 3) * H_ + p * 8 + (lr & 7);// global gate row
    int kb = (lane >> 4) * 8;
    int arow = mt * 16 + (lane & 15);          // A-fragment row (batch index)

    // preload weight fragments into registers (192 VGPRs)
    short8 B0[16], B1[32];
    #pragma unroll
    for (int ks = 0; ks < 16; ks++) {
        const float* s0 = Whh0 + (size_t)gr * H_ + ks * 32 + kb;
        const float* s1 = Wih1 + (size_t)gr * H_ + ks * 32 + kb;
        const float* s2 = Whh1 + (size_t)gr * H_ + ks * 32 + kb;
        float4 a = *(const float4*)(s0), b = *(const float4*)(s0 + 4);
        short8 t0; t0[0]=f2bf(a.x);t0[1]=f2bf(a.y);t0[2]=f2bf(a.z);t0[3]=f2bf(a.w);
                   t0[4]=f2bf(b.x);t0[5]=f2bf(b.y);t0[6]=f2bf(b.z);t0[7]=f2bf(b.w);
        B0[ks] = t0;
        a = *(const float4*)(s1); b = *(const float4*)(s1 + 4);
        short8 t1; t1[0]=f2bf(a.x);t1[1]=f2bf(a.y);t1[2]=f2bf(a.z);t1[3]=f2bf(a.w);
                   t1[4]=f2bf(b.x);t1[5]=f2bf(b.y);t1[6]=f2bf(b.z);t1[7]=f2bf(b.w);
        B1[ks] = t1;
        a = *(const float4*)(s2); b = *(const float4*)(s2 + 4);
        short8 t2; t2[0]=f2bf(a.x);t2[1]=f2bf(a.y);t2[2]=f2bf(a.z);t2[3]=f2bf(a.w);
                   t2[4]=f2bf(b.x);t2[5]=f2bf(b.y);t2[6]=f2bf(b.z);t2[7]=f2bf(b.w);
        B1[16 + ks] = t2;
    }
    if (tid < 32) {
        int g = (tid >> 3) * H_ + p * 8 + (tid & 7);
        bias1[tid] = bih1[g] + bhh1[g];
    }
    int uu = tid & 7, b8 = tid >> 3;
    c0s[uu * 33 + b8] = init_c[(size_t)b8 * H_ + p * 8 + uu];
    c1s[uu * 33 + b8] = init_c[(size_t)B_ * H_ + (size_t)b8 * H_ + p * 8 + uu];
    __syncthreads();

    unsigned bar_target = 0;
    const float* gptr = G0 + (size_t)b8 * S_ * G4H + p * 8 + uu;

    for (int it = 0; it <= S_; it++) {
        // h0 state[it] and h1 state[it-1] A-fragments, direct to registers
        const unsigned short* p0 = h0buf + (size_t)(it & 1) * (B_ * H_)
                                 + (size_t)arow * H_ + kb;
        const unsigned short* p1 = h1buf + (size_t)((it + 1) & 1) * (B_ * H_)
                                 + (size_t)arow * H_ + kb;
        short8 F0[16], F1[16];
        CLDALL(F0, p0);
        CLDALL(F1, p1);

        // G0[t] gate pre-activations (plain loads; compiler inserts its own waits)
        float gpre0 = 0.f, gpre1 = 0.f, gpre2 = 0.f, gpre3 = 0.f;
        if (it < S_) {
            const float* gsrc = gptr + (size_t)it * G4H;
            gpre0 = gsrc[0]; gpre1 = gsrc[H_]; gpre2 = gsrc[2 * H_]; gpre3 = gsrc[3 * H_];
        }

        // single drain; ties make fragment registers unusable until data lands
        asm volatile("s_waitcnt vmcnt(0)"
            : "+v"(F0[0]),"+v"(F0[1]),"+v"(F0[2]),"+v"(F0[3]),
              "+v"(F0[4]),"+v"(F0[5]),"+v"(F0[6]),"+v"(F0[7]),
              "+v"(F0[8]),"+v"(F0[9]),"+v"(F0[10]),"+v"(F0[11]),
              "+v"(F0[12]),"+v"(F0[13]),"+v"(F0[14]),"+v"(F0[15]),
              "+v"(F1[0]),"+v"(F1[1]),"+v"(F1[2]),"+v"(F1[3]),
              "+v"(F1[4]),"+v"(F1[5]),"+v"(F1[6]),"+v"(F1[7]),
              "+v"(F1[8]),"+v"(F1[9]),"+v"(F1[10]),"+v"(F1[11]),
              "+v"(F1[12]),"+v"(F1[13]),"+v"(F1[14]),"+v"(F1[15]));

        f32x4 acc0 = {0.f,0.f,0.f,0.f};
        f32x4 a1a  = {0.f,0.f,0.f,0.f};
        f32x4 a1b  = {0.f,0.f,0.f,0.f};
        #pragma unroll
        for (int ks = 0; ks < 16; ks++) {
            acc0 = __builtin_amdgcn_mfma_f32_16x16x32_bf16(F0[ks], B0[ks],      acc0, 0, 0, 0);
            a1a  = __builtin_amdgcn_mfma_f32_16x16x32_bf16(F0[ks], B1[ks],      a1a,  0, 0, 0);
            a1b  = __builtin_amdgcn_mfma_f32_16x16x32_bf16(F1[ks], B1[16 + ks], a1b,  0, 0, 0);
        }
        #pragma unroll
        for (int r = 0; r < 4; r++) {
            int row = mt * 16 + (lane >> 4) * 4 + r;
            g0l[row * 33 + lr] = acc0[r];
            g1l[row * 33 + lr] = a1a[r] + a1b[r];
        }
        __syncthreads();

        if (it < S_) {
            float iv = g0l[b8 * 33 + uu]       + gpre0;
            float fv = g0l[b8 * 33 + 8 + uu]   + gpre1;
            float gv = g0l[b8 * 33 + 16 + uu]  + gpre2;
            float ov = g0l[b8 * 33 + 24 + uu]  + gpre3;
            float c = c0s[uu * 33 + b8];
            c = sigf(fv) * c + sigf(iv) * tanhf(gv);
            c0s[uu * 33 + b8] = c;
            float h = sigf(ov) * tanhf(c);
            unsigned short hb = f2bf(h);
            float hn = __shfl_down(h, 1, 64);          // partner (uu+1) value
            if (!(uu & 1)) {
                unsigned pk = (unsigned)hb | ((unsigned)f2bf(hn) << 16);
                unsigned short* dst = h0buf + (size_t)((it + 1) & 1) * (B_ * H_)
                                    + (size_t)b8 * H_ + p * 8 + uu;
                CST32(dst, pk);
            }
        }
        if (it >= 1) {
            float iv = g1l[b8 * 33 + uu]       + bias1[uu];
            float fv = g1l[b8 * 33 + 8 + uu]   + bias1[8 + uu];
            float gv = g1l[b8 * 33 + 16 + uu]  + bias1[16 + uu];
            float ov = g1l[b8 * 33 + 24 + uu]  + bias1[24 + uu];
            float c = c1s[uu * 33 + b8];
            c = sigf(fv) * c + sigf(iv) * tanhf(gv);
            c1s[uu * 33 + b8] = c;
            float h = sigf(ov) * tanhf(c);
            unsigned short hb = f2bf(h);
            float hn = __shfl_down(h, 1, 64);
            if (!(uu & 1)) {
                unsigned pk = (unsigned)hb | ((unsigned)f2bf(hn) << 16);
                unsigned short* dst = h1buf + (size_t)(it & 1) * (B_ * H_)
                                    + (size_t)b8 * H_ + p * 8 + uu;
                CST32(dst, pk);
            }
            lstm_out[(size_t)(b8 * S_ + (it - 1)) * H_ + p * 8 + uu] = h;
        }

        if (it < S_) {
            // grid barrier: drain own coherent stores, then arrive; spin on
            // relaxed agent load (all 64 blocks co-resident by construction)
            bar_target += 64;
            asm volatile("s_waitcnt vmcnt(0)" ::: "memory");
            __syncthreads();
            if (tid == 0) {
                __hip_atomic_fetch_add(bar, 1u, __ATOMIC_RELAXED, __HIP_MEMORY_SCOPE_AGENT);
                while (__hip_atomic_load(bar, __ATOMIC_RELAXED, __HIP_MEMORY_SCOPE_AGENT) < bar_target) {
                    __builtin_amdgcn_s_sleep(1);
                }
            }
            __syncthreads();
        }
    }
}

// ---------------- gathered prediction + BCE ----------------
__global__ __launch_bounds__(256) void pred_kernel(
    const float* __restrict__ lstm_out, const float* __restrict__ cn,
    const float* __restrict__ Wp, const float* __restrict__ bp,
    const int* __restrict__ qt, const float* __restrict__ target,
    float* __restrict__ out, float* __restrict__ accum)
{
    int wv = (blockIdx.x * 256 + threadIdx.x) >> 6;   // one wave per row
    int lane = threadIdx.x & 63;
    if (wv >= NROW) return;
    int q = qt[wv];
    const float* wrow = Wp + (size_t)q * (H_ + NF_);
    const float* hrow = lstm_out + (size_t)wv * H_;
    float part = 0.f;
    #pragma unroll
    for (int i = 0; i < H_ / 64; i++) part += hrow[lane + i * 64] * wrow[lane + i * 64];
    if (lane < NF_) part += cn[(size_t)wv * NF_ + lane] * wrow[H_ + lane];
    #pragma unroll
    for (int off = 32; off; off >>= 1) part += __shfl_down(part, off, 64);
    if (lane == 0) {
        float x = part + bp[q];
        float t = target[wv];
        float mask = (q > 0) ? 1.f : 0.f;
        out[1 + wv] = mask / (1.f + __expf(-x));
        out[1 + NROW + wv] = t * mask;
        float bce = fmaxf(x, 0.f) - x * t + log1pf(__expf(-fabsf(x)));
        atomicAdd(&accum[0], bce * mask);
        atomicAdd(&accum[1], mask);
    }
}

__global__ void final_kernel(const float* __restrict__ accum, float* __restrict__ out)
{
    out[0] = accum[0] / accum[1];
}

extern "C" void kernel_launch(void* const* d_in, const int* in_sizes, int n_in,
                              void* d_out, int out_size, void* d_ws, size_t ws_size,
                              hipStream_t stream)
{
    (void)in_sizes; (void)n_in; (void)out_size; (void)ws_size;
    const int*   x_data = (const int*)  d_in[0];
    const int*   q_t    = (const int*)  d_in[1];
    const float* target = (const float*)d_in[2];
    const float* rep    = (const float*)d_in[3];
    const float* past   = (const float*)d_in[4];
    const float* seq    = (const float*)d_in[5];
    const float* embed  = (const float*)d_in[6];
    const float* Wih0   = (const float*)d_in[7];
    const float* Whh0   = (const float*)d_in[8];
    const float* bih0   = (const float*)d_in[9];
    const float* bhh0   = (const float*)d_in[10];
    const float* Wih1   = (const float*)d_in[11];
    const float* Whh1   = (const float*)d_in[12];
    const float* bih1   = (const float*)d_in[13];
    const float* bhh1   = (const float*)d_in[14];
    const float* Wp     = (const float*)d_in[15];
    const float* bp     = (const float*)d_in[16];
    const float* C      = (const float*)d_in[17];
    const float* init_h = (const float*)d_in[18];
    const float* init_c = (const float*)d_in[19];

    char* ws = (char*)d_ws;
    float*          G0    = (float*)         (ws + OFF_G0);
    float*          lstm  = (float*)         (ws + OFF_LSTM);
    float*          ct    = (float*)         (ws + OFF_CT);
    float*          cn    = (float*)         (ws + OFF_CN);
    unsigned short* h0buf = (unsigned short*)(ws + OFF_H0);
    unsigned short* h1buf = (unsigned short*)(ws + OFF_H1);
    unsigned*       sync  = (unsigned*)      (ws + OFF_SYNC);
    unsigned short* wb    = (unsigned short*)(ws + OFF_WB);
    float* out = (float*)d_out;

    prep_kernel<<<540, 256, 0, stream>>>(C, rep, past, seq, init_h, ct, cn, h0buf, h1buf, sync);
    prepw_kernel<<<(G4H * KP_ + 255) / 256, 256, 0, stream>>>(Wih0, wb);
    g0_kernel<<<6400, 256, 0, stream>>>(x_data, embed, wb, bih0, bhh0, ct, G0);
    scan_kernel<<<64, 256, 0, stream>>>(G0, Whh0, Wih1, Whh1, bih1, bhh1, init_c,
                                        h0buf, h1buf, lstm, sync);
    pred_kernel<<<NROW / 4, 256, 0, stream>>>(lstm, cn, Wp, bp, q_t, target, out,
                                              (float*)(sync + 1));
    final_kernel<<<1, 1, 0, stream>>>((const float*)(sync + 1), out);
}